// Round 19
// baseline (153.645 us; speedup 1.0000x reference)
//
#include <hip/hip_runtime.h>
#include <stdint.h>

typedef float f32x2 __attribute__((ext_vector_type(2)));
typedef float f32x4 __attribute__((ext_vector_type(4)));

#define ROWS   32
#define TILE_F (ROWS * 310)   // 9920 floats
#define NTPB   4
#define PSTR   82             // partials [row][8 slots x 10]: 82%32=18, gcd2 -> 16 banks
#define CP_OFF (ROWS * PSTR)  // 2624; coeff partials [row][18]
#define CPSTR  18
#define H1_OFF 3200           // h1 [row][14]
#define H1STR  14
#define A_F    3840           // A region [0,3840): covers all scratch, staged late
#define APW    480            // A floats/wave-eighth: 1 w16 + 224-float tail (56 lanes)
#define BPW    760            // B floats/wave-eighth: 2 w16 + 248-float tail (62 lanes)
#define LDSF   (TILE_F + 64)  // + ccs
#define LDS_BYTES (LDSF * 4)  // 39,936 B -> 4 blocks/CU (32 waves/CU)

__device__ __forceinline__ float leaky(float v) { return fmaxf(v, 0.01f * v); }
__device__ __forceinline__ f32x2 leaky2(f32x2 v) {
    return __builtin_elementwise_max(v, v * 0.01f);
}

// global->LDS direct, 16 B/lane; side-effecting. All sources 16B-aligned.
__device__ __forceinline__ void gload16(const float* g, float* l) {
    auto gp = reinterpret_cast<const float __attribute__((address_space(1)))*>(
        reinterpret_cast<uintptr_t>(g));
    auto lp = reinterpret_cast<float __attribute__((address_space(3)))*>(
        reinterpret_cast<uintptr_t>(l));
    __builtin_amdgcn_global_load_lds(gp, lp, 16, 0, 0);
}

// Region A: 480 floats/wave = 1 full w16 + 224-float tail (56 lanes)
__device__ __forceinline__ void stage_A(const float* src, float* dst, int lane) {
    gload16(src, dst);
    if (lane < 56) gload16(src + 256, dst + 256);
}
// Region B: 760 floats/wave = 2 full w16 + 248-float tail (62 lanes)
__device__ __forceinline__ void stage_B(const float* src, float* dst, int lane) {
    gload16(src, dst);
    gload16(src + 256, dst + 256);
    if (lane < 62) gload16(src + 512, dst + 512);
}

__global__ __launch_bounds__(512, 8) void gen_mlp_r19(
    const float* __restrict__ x, const float* __restrict__ data_t,
    const float* __restrict__ W1, const float* __restrict__ b1,
    const float* __restrict__ W2, const float* __restrict__ b2,
    const float* __restrict__ W3, const float* __restrict__ b3,
    float* __restrict__ out)
{
    extern __shared__ float lds[];
    float* buf = lds;                 // x tile; A-region doubles as scratch
    float* ccs = lds + TILE_F;        // 64 floats: final (c0,c1) per row

    const int t     = threadIdx.x;
    const int lane  = t & 63;
    const int row   = lane & 31;                               // 2 lanes per row
    const int kh    = lane >> 5;                               // k-half within wave slice
    const int wq    = __builtin_amdgcn_readfirstlane(t >> 6);  // wave 0..7

    const int tile0 = blockIdx.x * NTPB;

    // ---- prologue: stage tile0 fully (5 async ops/wave) ----
    {
        const float* g = x + (size_t)tile0 * TILE_F;
        stage_A(g + wq * APW + lane * 4,       buf + wq * APW,       lane);
        stage_B(g + A_F + wq * BPW + lane * 4, buf + A_F + wq * BPW, lane);
    }
    asm volatile("s_waitcnt vmcnt(0)" ::: "memory");
    __builtin_amdgcn_s_barrier();

    #pragma unroll 1
    for (int it = 0; it < NTPB; ++it) {
        const int tile  = tile0 + it;
        const int tnext = (it + 1 < NTPB) ? tile + 1 : tile;   // last: L2-warm refetch
        const float* gnext = x + (size_t)tnext * TILE_F;

        // ---- data_t loads FIRST (oldest vm ops of the iteration) ----
        const f32x4* dt4 = (const f32x4*)data_t + (size_t)tile * (ROWS * 25);
        f32x4 tv0 = dt4[t], tv1;
        if (t < 288) tv1 = dt4[512 + t];

        // ---- x: my (row, k-half of wave slice) -> registers ----
        // wave wq covers k [40wq, 40wq+40) (wq7: 30); kh splits 20/20 (wq7: 20/10)
        float xk[20];
        int nk = 20;
        {
            const float* xr = buf + row * 310 + wq * 40 + kh * 20;
            if (wq == 7 && kh == 1) {
                nk = 10;
                #pragma unroll
                for (int q = 0; q < 5; ++q)
                    *(f32x2*)&xk[2 * q] = *(const f32x2*)(xr + 2 * q);
            } else {
                #pragma unroll
                for (int q = 0; q < 10; ++q)
                    *(f32x2*)&xk[2 * q] = *(const f32x2*)(xr + 2 * q);
            }
        }
        asm volatile("s_waitcnt lgkmcnt(0)" ::: "memory");
        __builtin_amdgcn_s_barrier();     // (a0): buf free (x lives in regs)

        // ---- stage next tile's B region ----
        stage_B(gnext + A_F + wq * BPW + lane * 4, buf + A_F + wq * BPW, lane);

        // ---- L1: weights via s_load; k-half fold via shfl_xor(32) ----
        float acc[10] = {0,0,0,0,0,0,0,0,0,0};
        {
            const float* Wb = W1 + (wq * 40 + kh * 20) * 10;   // wave-uniform
            if (wq == 7 && kh == 1) {
                #pragma unroll
                for (int k = 0; k < 10; ++k)
                    #pragma unroll
                    for (int j = 0; j < 10; ++j)
                        acc[j] = fmaf(xk[k], Wb[k * 10 + j], acc[j]);
            } else {
                #pragma unroll
                for (int k = 0; k < 20; ++k)
                    #pragma unroll
                    for (int j = 0; j < 10; ++j)
                        acc[j] = fmaf(xk[k], Wb[k * 10 + j], acc[j]);
            }
        }
        #pragma unroll
        for (int j = 0; j < 10; ++j)
            acc[j] += __shfl_xor(acc[j], 32, 64);   // fold k-halves

        if (kh == 0) {   // ---- partials [row][wq][10] into A-region scratch ----
            float* pw = buf + row * PSTR + wq * 10;
            #pragma unroll
            for (int j = 0; j < 5; ++j)
                *(f32x2*)(pw + 2 * j) = (f32x2){acc[2 * j], acc[2 * j + 1]};
        }
        asm volatile("s_waitcnt lgkmcnt(0)" ::: "memory");
        __builtin_amdgcn_s_barrier();     // (a)

        // ---- distributed h1: 320 jobs (row,j) over threads t<320 ----
        if (t < 320) {
            const int hr = t / 10, hj = t - 10 * hr;   // magic-mul
            const float* pr = buf + hr * PSTR + hj;
            float s = b1[hj];
            #pragma unroll
            for (int sl = 0; sl < 8; ++sl) s += pr[sl * 10];
            buf[H1_OFF + hr * H1STR + hj] = leaky(s);
        }
        asm volatile("s_waitcnt lgkmcnt(0)" ::: "memory");
        __builtin_amdgcn_s_barrier();     // (h): h1 ready

        // ---- h1 for my row (lane halves broadcast-share) ----
        float h1[10];
        {
            const float* hr = buf + H1_OFF + row * H1STR;
            #pragma unroll
            for (int m = 0; m < 5; ++m) {
                f32x2 v = *(const f32x2*)(hr + 2 * m);
                h1[2 * m] = v.x; h1[2 * m + 1] = v.y;
            }
        }

        // ---- L2 j-slice (16 outs, duplicated across lane halves) + L3 ----
        float hh[16];
        #pragma unroll
        for (int jj = 0; jj < 16; ++jj) hh[jj] = b2[wq * 16 + jj];
        #pragma unroll
        for (int k = 0; k < 10; ++k) {
            #pragma unroll
            for (int jj = 0; jj < 16; ++jj)
                hh[jj] = fmaf(h1[k], W2[k * 128 + wq * 16 + jj], hh[jj]);
        }
        f32x2 p = {0.f, 0.f};
        #pragma unroll
        for (int jj = 0; jj < 16; ++jj) {
            const float s = leaky(hh[jj]);
            p.x = fmaf(s, W3[(wq * 16 + jj) * 2 + 0], p.x);
            p.y = fmaf(s, W3[(wq * 16 + jj) * 2 + 1], p.y);
        }

        // ---- coeff partials [row][18] (kh==0 lanes only; kh1 duplicates) ----
        if (kh == 0)
            *(f32x2*)(buf + CP_OFF + row * CPSTR + 2 * wq) = p;
        asm volatile("s_waitcnt lgkmcnt(0)" ::: "memory");
        __builtin_amdgcn_s_barrier();     // (b)

        if (wq == 0 && kh == 0) {   // 8 x b64 reads, 16-bank spread
            const float* cb = buf + CP_OFF + row * CPSTR;
            f32x2 q = {b3[0], b3[1]};
            #pragma unroll
            for (int i = 0; i < 8; ++i) {
                f32x2 v = *(const f32x2*)(cb + 2 * i);
                q.x += v.x;
                q.y += v.y;
            }
            *(f32x2*)(ccs + 2 * row) = leaky2(q);
        }
        asm volatile("s_waitcnt lgkmcnt(0)" ::: "memory");
        __builtin_amdgcn_s_barrier();     // (b2): ccs ready, A-scratch dead

        // ---- stage next tile's A region (scratch dead now) ----
        stage_A(gnext + wq * APW + lane * 4, buf + wq * APW, lane);

        // ---- epilogue: out = t*(c0 + c1*t); 800 f32x4 over 512 threads ----
        f32x4* o4 = (f32x4*)out + (size_t)tile * (ROWS * 25);
        {
            f32x2 cc = *(const f32x2*)(ccs + 2 * (t / 25));
            o4[t] = tv0 * (tv0 * cc.y + cc.x);
        }
        if (t < 288) {
            const int idx = 512 + t;
            f32x2 cc = *(const f32x2*)(ccs + 2 * (idx / 25));
            o4[idx] = tv1 * (tv1 * cc.y + cc.x);
        }

        // ---- (d): all 5 staging ops of tile it+1 retired; 2 stores ride ----
        asm volatile("s_waitcnt vmcnt(2)" ::: "memory");
        __builtin_amdgcn_s_barrier();
    }
}

extern "C" void kernel_launch(void* const* d_in, const int* in_sizes, int n_in,
                              void* d_out, int out_size, void* d_ws, size_t ws_size,
                              hipStream_t stream) {
    const float* x      = (const float*)d_in[0];
    const float* data_t = (const float*)d_in[1];
    const float* W1     = (const float*)d_in[2];
    const float* b1     = (const float*)d_in[3];
    const float* W2     = (const float*)d_in[4];
    const float* b2     = (const float*)d_in[5];
    const float* W3     = (const float*)d_in[6];
    const float* b3     = (const float*)d_in[7];
    float* out = (float*)d_out;

    hipFuncSetAttribute((const void*)gen_mlp_r19,
                        hipFuncAttributeMaxDynamicSharedMemorySize, LDS_BYTES);
    // 1024 blocks x 512 threads (8 waves) x 4 tiles of 32 rows = 131072 rows;
    // 4 blocks/CU (39,936 B LDS each) = 32 waves/CU, 4 convoy groups.
    gen_mlp_r19<<<1024, 512, LDS_BYTES, stream>>>(x, data_t, W1, b1, W2, b2, W3, b3, out);
}